// Round 1
// baseline (427.286 us; speedup 1.0000x reference)
//
#include <hip/hip_runtime.h>

// Linear(int8-weight, block-sparse) -> quantize -> dequantize, as one fp16 MFMA GEMM.
// out[n,o] = dq(q( (x @ (w_q*mask)^T) * w_scale + bias ))
// N=8192 tokens, O=4096, K=4096. Mask granularity 1 row x 4 cols.
//
// Key numerics: w_q*mask are integers in [-127,127] -> exact in fp16.
// x->fp16 rounding gives y-error rms ~5e-3 << out_scale=0.05, so the
// quantized output differs from the fp32 reference by at most one quant
// step (0.05) < threshold 0.128.

#define M_TOK 8192
#define O_FEAT 4096
#define K_FEAT 4096

#define TM 128
#define TN 128
#define TK 64

using f16x8 = __attribute__((ext_vector_type(8))) _Float16;
using f32x4 = __attribute__((ext_vector_type(4))) float;

// ---------------- fp32 -> fp16 conversion of activations ----------------
__global__ __launch_bounds__(256) void cvt_x_kernel(const float* __restrict__ x,
                                                    _Float16* __restrict__ xf) {
    size_t i = ((size_t)blockIdx.x * 256 + threadIdx.x) * 8;
    float4 v0 = *reinterpret_cast<const float4*>(x + i);
    float4 v1 = *reinterpret_cast<const float4*>(x + i + 4);
    f16x8 h;
    h[0] = (_Float16)v0.x; h[1] = (_Float16)v0.y;
    h[2] = (_Float16)v0.z; h[3] = (_Float16)v0.w;
    h[4] = (_Float16)v1.x; h[5] = (_Float16)v1.y;
    h[6] = (_Float16)v1.z; h[7] = (_Float16)v1.w;
    *reinterpret_cast<f16x8*>(xf + i) = h;
}

// ------------- fuse block mask into fp16 weights (exact ints) -----------
__global__ __launch_bounds__(256) void cvt_w_kernel(const float* __restrict__ wq,
                                                    const int* __restrict__ mask,
                                                    _Float16* __restrict__ wf) {
    size_t i = ((size_t)blockIdx.x * 256 + threadIdx.x) * 8;  // 8 weights = 2 mask blocks
    float4 v0 = *reinterpret_cast<const float4*>(wq + i);
    float4 v1 = *reinterpret_cast<const float4*>(wq + i + 4);
    int2 mv = *reinterpret_cast<const int2*>(mask + i / 4);
    float m0 = mv.x ? 1.0f : 0.0f;
    float m1 = mv.y ? 1.0f : 0.0f;
    f16x8 h;
    h[0] = (_Float16)(v0.x * m0); h[1] = (_Float16)(v0.y * m0);
    h[2] = (_Float16)(v0.z * m0); h[3] = (_Float16)(v0.w * m0);
    h[4] = (_Float16)(v1.x * m1); h[5] = (_Float16)(v1.y * m1);
    h[6] = (_Float16)(v1.z * m1); h[7] = (_Float16)(v1.w * m1);
    *reinterpret_cast<f16x8*>(wf + i) = h;
}

// ---------------- fp16 MFMA GEMM, m97 structure (128x128, BK=64) --------
// A [M][K] fp16 row-major, B [O][K] fp16 row-major (i.e. B^T GEMM).
// 4 waves in 2x2, each owns a 64x64 output sub-tile as 4x4 16x16 fragments.
__global__ __launch_bounds__(256) void gemm_kernel(const _Float16* __restrict__ A,
                                                   const _Float16* __restrict__ B,
                                                   const float* __restrict__ bias,
                                                   const float* __restrict__ wsp,
                                                   const float* __restrict__ osp,
                                                   float* __restrict__ C) {
    __shared__ _Float16 As[TM][TK];  // 16 KiB
    __shared__ _Float16 Bs[TN][TK];  // 16 KiB

    const int tid = threadIdx.x;
    const int bm = blockIdx.x >> 5;   // 64 row tiles
    const int bn = blockIdx.x & 31;   // 32 col tiles

    const int lane = tid & 63;
    const int wid  = tid >> 6;
    const int wm   = wid >> 1;        // 0..1
    const int wn   = wid & 1;         // 0..1
    const int lr   = lane & 15;       // fragment row (A) / col (B,C)
    const int kq   = lane >> 4;       // 0..3 k-chunk / C row group

    f32x4 acc[4][4] = {};

    // staging decomposition: 256 threads * 16 B = 4 KiB per issue; tile = 16 KiB -> 4 issues
    const int srow = tid >> 3;        // 0..31 rows per issue
    const int scol = (tid & 7) * 8;   // fp16 col offset (16 B granules)

    const _Float16* Ag = A + (size_t)(bm * TM) * K_FEAT;
    const _Float16* Bg = B + (size_t)(bn * TN) * K_FEAT;

    for (int k0 = 0; k0 < K_FEAT; k0 += TK) {
#pragma unroll
        for (int is = 0; is < 4; ++is) {
            __builtin_amdgcn_global_load_lds(
                (const __attribute__((address_space(1))) void*)(const void*)(Ag + (size_t)(is * 32 + srow) * K_FEAT + k0 + scol),
                (__attribute__((address_space(3))) void*)(void*)(&As[is * 32 + srow][scol]),
                16, 0, 0);
            __builtin_amdgcn_global_load_lds(
                (const __attribute__((address_space(1))) void*)(const void*)(Bg + (size_t)(is * 32 + srow) * K_FEAT + k0 + scol),
                (__attribute__((address_space(3))) void*)(void*)(&Bs[is * 32 + srow][scol]),
                16, 0, 0);
        }
        __syncthreads();  // drains vmcnt, publishes LDS tiles

#pragma unroll
        for (int kk = 0; kk < TK; kk += 32) {
            f16x8 af[4], bf[4];
#pragma unroll
            for (int mi = 0; mi < 4; ++mi)
                af[mi] = *reinterpret_cast<const f16x8*>(&As[wm * 64 + mi * 16 + lr][kk + kq * 8]);
#pragma unroll
            for (int ni = 0; ni < 4; ++ni)
                bf[ni] = *reinterpret_cast<const f16x8*>(&Bs[wn * 64 + ni * 16 + lr][kk + kq * 8]);
#pragma unroll
            for (int mi = 0; mi < 4; ++mi)
#pragma unroll
                for (int ni = 0; ni < 4; ++ni)
                    acc[mi][ni] = __builtin_amdgcn_mfma_f32_16x16x32_f16(af[mi], bf[ni], acc[mi][ni], 0, 0, 0);
        }
        __syncthreads();  // protect LDS before next stage overwrites
    }

    // ---------------- fused epilogue: scale + bias + quant + dequant ----------------
    const float wscale = wsp[0];
    const float oscale = osp[0];

    const int row0 = bm * TM + wm * 64;
    const int col0 = bn * TN + wn * 64;
#pragma unroll
    for (int ni = 0; ni < 4; ++ni) {
        const int col = col0 + ni * 16 + lr;
        const float bcol = bias[col];
#pragma unroll
        for (int mi = 0; mi < 4; ++mi) {
#pragma unroll
            for (int j = 0; j < 4; ++j) {
                const int row = row0 + mi * 16 + kq * 4 + j;
                float y = acc[mi][ni][j] * wscale + bcol;
                float q = rintf(y / oscale);          // round-half-even, matches jnp.round
                q = fminf(fmaxf(q, -128.0f), 127.0f); // QMIN..QMAX
                C[(size_t)row * O_FEAT + col] = q * oscale;
            }
        }
    }
}

extern "C" void kernel_launch(void* const* d_in, const int* in_sizes, int n_in,
                              void* d_out, int out_size, void* d_ws, size_t ws_size,
                              hipStream_t stream) {
    const float* x        = (const float*)d_in[0];  // [8192,4096] fp32
    const float* wq       = (const float*)d_in[1];  // [4096,4096] fp32 (int8 values)
    const float* bias     = (const float*)d_in[2];  // [4096]
    const float* w_scale  = (const float*)d_in[3];  // scalar
    const float* out_scale= (const float*)d_in[4];  // scalar
    const int*   mask     = (const int*)d_in[5];    // [4096,1024] int32
    float* out = (float*)d_out;

    _Float16* xf = (_Float16*)d_ws;                                  // 64 MiB
    _Float16* wf = (_Float16*)((char*)d_ws + (size_t)M_TOK * K_FEAT * 2);  // +32 MiB

    // x: 33.5M elems / 8 per thread / 256 per block
    cvt_x_kernel<<<(M_TOK * (size_t)K_FEAT) / 8 / 256, 256, 0, stream>>>(x, xf);
    // w: 16.8M elems / 8 per thread / 256 per block
    cvt_w_kernel<<<(O_FEAT * (size_t)K_FEAT) / 8 / 256, 256, 0, stream>>>(wq, mask, wf);

    // GEMM: (8192/128) x (4096/128) = 64*32 = 2048 blocks
    gemm_kernel<<<dim3((M_TOK / TM) * (O_FEAT / TN)), 256, 0, stream>>>(
        xf, wf, bias, w_scale, out_scale, out);
}

// Round 2
// 309.077 us; speedup vs baseline: 1.3825x; 1.3825x over previous
//
#include <hip/hip_runtime.h>

// Linear(int8-weight, block-sparse) -> quantize -> dequantize, as one fp16 MFMA GEMM.
// out[n,o] = dq(q( (x @ (w_q*mask)^T) * w_scale + bias ))
// N=8192 tokens, O=4096, K=4096.
//
// Numerics: w_q*mask are integers in [-127,127] -> exact in fp16; x->fp16
// rounding error << out_scale quant step (validated round 1: absmax 0.0625).
//
// GEMM: 256x256 8-phase template (T2 LDS swizzle + T3/T4 counted vmcnt +
// T5 setprio). K-tiles of 64 split into two 32-col half-tiles so each
// phase's ds_reads touch one K-half -> staged halves get >=4 phases of
// flight -> steady-state s_waitcnt vmcnt(6), never drained to 0 in-loop.

#define M_TOK 8192
#define O_FEAT 4096
#define K_FEAT 4096

#define BM 256
#define BN 256
#define BK 64
#define NT (K_FEAT / BK)   // 64 K-tiles

using f16x8 = __attribute__((ext_vector_type(8))) _Float16;
using f32x4 = __attribute__((ext_vector_type(4))) float;

#define BAR()    asm volatile("s_barrier" ::: "memory")
#define LGKM0()  asm volatile("s_waitcnt lgkmcnt(0)" ::: "memory")
#define VMCNT(n) asm volatile("s_waitcnt vmcnt(" #n ")" ::: "memory")
#define MFMA16(a, b, c) __builtin_amdgcn_mfma_f32_16x16x32_f16((a), (b), (c), 0, 0, 0)

// ---------------- fp32 -> fp16 conversion of activations ----------------
__global__ __launch_bounds__(256) void cvt_x_kernel(const float* __restrict__ x,
                                                    _Float16* __restrict__ xf) {
    size_t i = ((size_t)blockIdx.x * 256 + threadIdx.x) * 8;
    float4 v0 = *reinterpret_cast<const float4*>(x + i);
    float4 v1 = *reinterpret_cast<const float4*>(x + i + 4);
    f16x8 h;
    h[0] = (_Float16)v0.x; h[1] = (_Float16)v0.y;
    h[2] = (_Float16)v0.z; h[3] = (_Float16)v0.w;
    h[4] = (_Float16)v1.x; h[5] = (_Float16)v1.y;
    h[6] = (_Float16)v1.z; h[7] = (_Float16)v1.w;
    *reinterpret_cast<f16x8*>(xf + i) = h;
}

// ------------- fuse block mask into fp16 weights (exact ints) -----------
__global__ __launch_bounds__(256) void cvt_w_kernel(const float* __restrict__ wq,
                                                    const int* __restrict__ mask,
                                                    _Float16* __restrict__ wf) {
    size_t i = ((size_t)blockIdx.x * 256 + threadIdx.x) * 8;  // 8 weights = 2 mask blocks
    float4 v0 = *reinterpret_cast<const float4*>(wq + i);
    float4 v1 = *reinterpret_cast<const float4*>(wq + i + 4);
    int2 mv = *reinterpret_cast<const int2*>(mask + i / 4);
    float m0 = mv.x ? 1.0f : 0.0f;
    float m1 = mv.y ? 1.0f : 0.0f;
    f16x8 h;
    h[0] = (_Float16)(v0.x * m0); h[1] = (_Float16)(v0.y * m0);
    h[2] = (_Float16)(v0.z * m0); h[3] = (_Float16)(v0.w * m0);
    h[4] = (_Float16)(v1.x * m1); h[5] = (_Float16)(v1.y * m1);
    h[6] = (_Float16)(v1.z * m1); h[7] = (_Float16)(v1.w * m1);
    *reinterpret_cast<f16x8*>(wf + i) = h;
}

// ---------------- 256x256 8-phase fp16 MFMA GEMM ------------------------
// A [8192][4096] f16 row-major, B [4096][4096] f16 row-major (B^T GEMM).
// 8 waves (2Mx4N), per-wave 128x64 output, acc[8][4] 16x16 fragments.
// LDS: smem[buf][mat][khalf][256*32] f16 = 128 KiB.
// Swizzle: 16B granule-in-row kq -> kq ^ ((row>>1)&3); linear LDS dest +
// inverse-permuted global src (global_load_lds), same XOR on ds_read.
__global__ __launch_bounds__(512, 2) void gemm_kernel(const _Float16* __restrict__ A,
                                                      const _Float16* __restrict__ B,
                                                      const float* __restrict__ bias,
                                                      const float* __restrict__ wsp,
                                                      const float* __restrict__ osp,
                                                      float* __restrict__ C) {
    __shared__ __align__(16) _Float16 smem[2][2][2][BM * 32];

    const int tid  = threadIdx.x;
    const int lane = tid & 63;
    const int w    = tid >> 6;      // 0..7
    const int wm   = w >> 2;        // 0..1  (M half)
    const int wn   = w & 3;         // 0..3  (N quarter)
    const int lr   = lane & 15;     // fragment row/col
    const int kq   = lane >> 4;     // 0..3  k-granule

    const int bm = blockIdx.x >> 4; // 32 M-tiles
    const int bn = blockIdx.x & 15; // 16 N-tiles

    const _Float16* Abase = A + (size_t)(bm * BM) * K_FEAT;
    const _Float16* Bbase = B + (size_t)(bn * BN) * K_FEAT;

    // staging geometry: thread covers rows sr0, sr0+16 of a [256][32] half,
    // source col-granule inverse-swizzled so LDS stays linear.
    const int sr0  = w * 32 + (lane >> 2);
    const int csrc = (((lane & 3) ^ ((lane >> 3) & 3))) * 8;  // f16 offset in 32-col row

    auto stage = [&](int buf, int mat, int kh, const _Float16* gbase, int t) {
#pragma unroll
        for (int j = 0; j < 2; ++j) {
            const int r = sr0 + j * 16;
            const _Float16* src = gbase + (size_t)r * K_FEAT + t * BK + kh * 32 + csrc;
            _Float16* dst = &smem[buf][mat][kh][(w * 128 + j * 64 + lane) * 8];
            __builtin_amdgcn_global_load_lds(
                (const __attribute__((address_space(1))) void*)(const void*)src,
                (__attribute__((address_space(3))) void*)(void*)dst, 16, 0, 0);
        }
    };
    auto lda = [&](int buf, int kh, int m) -> f16x8 {
        const int r = wm * 128 + m * 16 + lr;
        return *reinterpret_cast<const f16x8*>(
            &smem[buf][0][kh][r * 32 + ((kq ^ ((r >> 1) & 3)) << 3)]);
    };
    auto ldb = [&](int buf, int kh, int n) -> f16x8 {
        const int r = wn * 64 + n * 16 + lr;
        return *reinterpret_cast<const f16x8*>(
            &smem[buf][1][kh][r * 32 + ((kq ^ ((r >> 1) & 3)) << 3)]);
    };

    f32x4 acc[8][4] = {};
    f16x8 a[8], bf[4];

    // prologue: tile0 fully + A_k0(1); first two halves done after vmcnt(6)
    stage(0, 0, 0, Abase, 0);   // A_k0(0)
    stage(0, 1, 0, Bbase, 0);   // B_k0(0)
    stage(0, 0, 1, Abase, 0);   // A_k1(0)
    stage(0, 1, 1, Bbase, 0);   // B_k1(0)
    stage(1, 0, 0, Abase, 1);   // A_k0(1)
    VMCNT(6);
    BAR();

    for (int s = 0; s < NT; ++s) {
        const int b = s & 1;

        // ---- P1: k-half 0, n 0-1 ----
        if (s + 1 < NT) stage(b ^ 1, 1, 0, Bbase, s + 1);   // B_k0(s+1)
#pragma unroll
        for (int m = 0; m < 8; ++m) a[m] = lda(b, 0, m);
        bf[0] = ldb(b, 0, 0);
        bf[1] = ldb(b, 0, 1);
        BAR();
        LGKM0();
        __builtin_amdgcn_s_setprio(1);
#pragma unroll
        for (int m = 0; m < 8; ++m) {
            acc[m][0] = MFMA16(a[m], bf[0], acc[m][0]);
            acc[m][1] = MFMA16(a[m], bf[1], acc[m][1]);
        }
        __builtin_amdgcn_s_setprio(0);
        BAR();

        // ---- P2: k-half 0, n 2-3 ----
        if (s + 1 < NT) stage(b ^ 1, 0, 1, Abase, s + 1);   // A_k1(s+1)
        bf[2] = ldb(b, 0, 2);
        bf[3] = ldb(b, 0, 3);
        BAR();
        LGKM0();
        __builtin_amdgcn_s_setprio(1);
#pragma unroll
        for (int m = 0; m < 8; ++m) {
            acc[m][2] = MFMA16(a[m], bf[2], acc[m][2]);
            acc[m][3] = MFMA16(a[m], bf[3], acc[m][3]);
        }
        __builtin_amdgcn_s_setprio(0);
        // guarantee A_k1(s), B_k1(s) before P3 reads; 3 newer halves may fly
        if (s == NT - 1) { VMCNT(0); } else { VMCNT(6); }
        BAR();

        // ---- P3: k-half 1, n 0-1 ----
        if (s + 1 < NT) stage(b ^ 1, 1, 1, Bbase, s + 1);   // B_k1(s+1)
#pragma unroll
        for (int m = 0; m < 8; ++m) a[m] = lda(b, 1, m);
        bf[0] = ldb(b, 1, 0);
        bf[1] = ldb(b, 1, 1);
        BAR();
        LGKM0();
        __builtin_amdgcn_s_setprio(1);
#pragma unroll
        for (int m = 0; m < 8; ++m) {
            acc[m][0] = MFMA16(a[m], bf[0], acc[m][0]);
            acc[m][1] = MFMA16(a[m], bf[1], acc[m][1]);
        }
        __builtin_amdgcn_s_setprio(0);
        BAR();

        // ---- P4: k-half 1, n 2-3 ----
        if (s + 2 < NT) stage(b, 0, 0, Abase, s + 2);       // A_k0(s+2)
        bf[2] = ldb(b, 1, 2);
        bf[3] = ldb(b, 1, 3);
        BAR();
        LGKM0();
        __builtin_amdgcn_s_setprio(1);
#pragma unroll
        for (int m = 0; m < 8; ++m) {
            acc[m][2] = MFMA16(a[m], bf[2], acc[m][2]);
            acc[m][3] = MFMA16(a[m], bf[3], acc[m][3]);
        }
        __builtin_amdgcn_s_setprio(0);
        // guarantee A_k0(s+1), B_k0(s+1) before next P1 reads
        if (s == NT - 2)      { VMCNT(4); }
        else if (s < NT - 2)  { VMCNT(6); }
        BAR();
    }

    // ---------------- fused epilogue: scale + bias + quant + dequant ----
    const float wscale = wsp[0];
    const float oscale = osp[0];
    const int row0 = bm * BM + wm * 128;
    const int col0 = bn * BN + wn * 64;
#pragma unroll
    for (int n = 0; n < 4; ++n) {
        const int col = col0 + n * 16 + lr;
        const float bc = bias[col];
#pragma unroll
        for (int m = 0; m < 8; ++m) {
#pragma unroll
            for (int j = 0; j < 4; ++j) {
                const int row = row0 + m * 16 + kq * 4 + j;
                float y = acc[m][n][j] * wscale + bc;
                float q = rintf(y / oscale);          // round-half-even, matches jnp.round
                q = fminf(fmaxf(q, -128.0f), 127.0f);
                C[(size_t)row * O_FEAT + col] = q * oscale;
            }
        }
    }
}

extern "C" void kernel_launch(void* const* d_in, const int* in_sizes, int n_in,
                              void* d_out, int out_size, void* d_ws, size_t ws_size,
                              hipStream_t stream) {
    const float* x        = (const float*)d_in[0];  // [8192,4096] fp32
    const float* wq       = (const float*)d_in[1];  // [4096,4096] fp32 (int8 values)
    const float* bias     = (const float*)d_in[2];  // [4096]
    const float* w_scale  = (const float*)d_in[3];  // scalar
    const float* out_scale= (const float*)d_in[4];  // scalar
    const int*   mask     = (const int*)d_in[5];    // [4096,1024] int32
    float* out = (float*)d_out;

    _Float16* xf = (_Float16*)d_ws;                                        // 64 MiB
    _Float16* wf = (_Float16*)((char*)d_ws + (size_t)M_TOK * K_FEAT * 2);  // +32 MiB

    cvt_x_kernel<<<(M_TOK * (size_t)K_FEAT) / 8 / 256, 256, 0, stream>>>(x, xf);
    cvt_w_kernel<<<(O_FEAT * (size_t)K_FEAT) / 8 / 256, 256, 0, stream>>>(wq, mask, wf);

    // (8192/256) x (4096/256) = 32*16 = 512 blocks, 512 threads
    gemm_kernel<<<dim3((M_TOK / BM) * (O_FEAT / BN)), 512, 0, stream>>>(
        xf, wf, bias, w_scale, out_scale, out);
}

// Round 3
// 300.245 us; speedup vs baseline: 1.4231x; 1.0294x over previous
//
#include <hip/hip_runtime.h>

// Linear(int8-weight, block-sparse) -> quantize -> dequantize, as one fp16 MFMA GEMM.
// out[n,o] = dq(q( (x @ (w_q*mask)^T) * w_scale + bias ))
// N=8192 tokens, O=4096, K=4096.
//
// Numerics: w_q*mask are integers in [-127,127] -> exact in fp16; x->fp16
// rounding error << out_scale quant step (validated: absmax 0.0625).
//
// GEMM: 256x256, BK=64, 8 waves (2Mx4N). Fragment-pipelined 4-phase K-loop:
// each phase's ds_reads are issued one phase ahead (compiler emits counted
// lgkmcnt), stages use global_load_lds with counted vmcnt(2) at the two
// publish points (end-P1 guards kh1(s), end-P3 guards kh0(s+1)).
// 6 barriers/K-tile. T2 granule-XOR swizzle keeps ds_read conflict-free
// (round 2: SQ_LDS_BANK_CONFLICT == 0).

#define M_TOK 8192
#define O_FEAT 4096
#define K_FEAT 4096

#define BM 256
#define BN 256
#define BK 64
#define NT (K_FEAT / BK)   // 64 K-tiles

using f16x8 = __attribute__((ext_vector_type(8))) _Float16;
using f32x4 = __attribute__((ext_vector_type(4))) float;

#define BAR()    asm volatile("s_barrier" ::: "memory")
#define VMCNT(n) asm volatile("s_waitcnt vmcnt(" #n ")" ::: "memory")
#define MFMA16(a, b, c) __builtin_amdgcn_mfma_f32_16x16x32_f16((a), (b), (c), 0, 0, 0)

// ---------------- fp32 -> fp16 conversion of activations ----------------
__global__ __launch_bounds__(256) void cvt_x_kernel(const float* __restrict__ x,
                                                    _Float16* __restrict__ xf) {
    size_t i = ((size_t)blockIdx.x * 256 + threadIdx.x) * 8;
    float4 v0 = *reinterpret_cast<const float4*>(x + i);
    float4 v1 = *reinterpret_cast<const float4*>(x + i + 4);
    f16x8 h;
    h[0] = (_Float16)v0.x; h[1] = (_Float16)v0.y;
    h[2] = (_Float16)v0.z; h[3] = (_Float16)v0.w;
    h[4] = (_Float16)v1.x; h[5] = (_Float16)v1.y;
    h[6] = (_Float16)v1.z; h[7] = (_Float16)v1.w;
    *reinterpret_cast<f16x8*>(xf + i) = h;
}

// ------------- fuse block mask into fp16 weights (exact ints) -----------
__global__ __launch_bounds__(256) void cvt_w_kernel(const float* __restrict__ wq,
                                                    const int* __restrict__ mask,
                                                    _Float16* __restrict__ wf) {
    size_t i = ((size_t)blockIdx.x * 256 + threadIdx.x) * 8;  // 8 weights = 2 mask blocks
    float4 v0 = *reinterpret_cast<const float4*>(wq + i);
    float4 v1 = *reinterpret_cast<const float4*>(wq + i + 4);
    int2 mv = *reinterpret_cast<const int2*>(mask + i / 4);
    float m0 = mv.x ? 1.0f : 0.0f;
    float m1 = mv.y ? 1.0f : 0.0f;
    f16x8 h;
    h[0] = (_Float16)(v0.x * m0); h[1] = (_Float16)(v0.y * m0);
    h[2] = (_Float16)(v0.z * m0); h[3] = (_Float16)(v0.w * m0);
    h[4] = (_Float16)(v1.x * m1); h[5] = (_Float16)(v1.y * m1);
    h[6] = (_Float16)(v1.z * m1); h[7] = (_Float16)(v1.w * m1);
    *reinterpret_cast<f16x8*>(wf + i) = h;
}

// ---------------- 256x256 fragment-pipelined fp16 MFMA GEMM -------------
// A [8192][4096] f16 row-major, B [4096][4096] f16 row-major (B^T GEMM).
// LDS: smem[buf][mat][khalf][256*32] f16 = 128 KiB.
// Swizzle: 16B granule-in-row kq -> kq ^ ((row>>1)&3); linear LDS dest +
// inverse-permuted global src (global_load_lds), same XOR on ds_read.
__global__ __launch_bounds__(512, 2) void gemm_kernel(const _Float16* __restrict__ A,
                                                      const _Float16* __restrict__ B,
                                                      const float* __restrict__ bias,
                                                      const float* __restrict__ wsp,
                                                      const float* __restrict__ osp,
                                                      float* __restrict__ C) {
    __shared__ __align__(16) _Float16 smem[2][2][2][BM * 32];

    const int tid  = threadIdx.x;
    const int lane = tid & 63;
    const int w    = tid >> 6;      // 0..7
    const int wm   = w >> 2;        // 0..1  (M half)
    const int wn   = w & 3;         // 0..3  (N quarter)
    const int lr   = lane & 15;     // fragment row/col
    const int kq   = lane >> 4;     // 0..3  k-granule

    const int bm = blockIdx.x >> 4; // 32 M-tiles
    const int bn = blockIdx.x & 15; // 16 N-tiles

    const _Float16* Abase = A + (size_t)(bm * BM) * K_FEAT;
    const _Float16* Bbase = B + (size_t)(bn * BN) * K_FEAT;

    // staging geometry: thread covers rows sr0, sr0+16 of a [256][32] half,
    // source col-granule inverse-swizzled so LDS stays linear.
    const int sr0  = w * 32 + (lane >> 2);
    const int csrc = (((lane & 3) ^ ((lane >> 3) & 3))) * 8;  // f16 offset in 32-col row

    auto stage = [&](int buf, int mat, int kh, const _Float16* gbase, int t) {
#pragma unroll
        for (int j = 0; j < 2; ++j) {
            const int r = sr0 + j * 16;
            const _Float16* src = gbase + (size_t)r * K_FEAT + t * BK + kh * 32 + csrc;
            _Float16* dst = &smem[buf][mat][kh][(w * 128 + j * 64 + lane) * 8];
            __builtin_amdgcn_global_load_lds(
                (const __attribute__((address_space(1))) void*)(const void*)src,
                (__attribute__((address_space(3))) void*)(void*)dst, 16, 0, 0);
        }
    };
    auto lda = [&](int buf, int kh, int m) -> f16x8 {
        const int r = wm * 128 + m * 16 + lr;
        return *reinterpret_cast<const f16x8*>(
            &smem[buf][0][kh][r * 32 + ((kq ^ ((r >> 1) & 3)) << 3)]);
    };
    auto ldb = [&](int buf, int kh, int n) -> f16x8 {
        const int r = wn * 64 + n * 16 + lr;
        return *reinterpret_cast<const f16x8*>(
            &smem[buf][1][kh][r * 32 + ((kq ^ ((r >> 1) & 3)) << 3)]);
    };

    f32x4 acc[8][4] = {};
    f16x8 a0[4], a1[4], b0[4], b1[4];  // a0: m0-3 frags, a1: m4-7; b0: kh-even, b1: kh-odd

    // ---- prologue: stage kh0(0); publish; prime P1 frags; stage kh1(0) ----
    stage(0, 0, 0, Abase, 0);
    stage(0, 1, 0, Bbase, 0);
    VMCNT(0);
    BAR();
#pragma unroll
    for (int m = 0; m < 4; ++m) a0[m] = lda(0, 0, m);
#pragma unroll
    for (int n = 0; n < 4; ++n) b0[n] = ldb(0, 0, n);
    stage(0, 0, 1, Abase, 0);
    stage(0, 1, 1, Bbase, 0);

    for (int s = 0; s < NT; ++s) {
        const int b  = s & 1;
        const int nb = b ^ 1;

        // ---- P1: prefetch a47_k0; stage A_k0(s+1); MFMA m0-3 x kh0 ----
#pragma unroll
        for (int m = 0; m < 4; ++m) a1[m] = lda(b, 0, 4 + m);
        if (s + 1 < NT) stage(nb, 0, 0, Abase, s + 1);
        BAR();
        __builtin_amdgcn_s_setprio(1);
#pragma unroll
        for (int m = 0; m < 4; ++m)
#pragma unroll
            for (int n = 0; n < 4; ++n)
                acc[m][n] = MFMA16(a0[m], b0[n], acc[m][n]);
        __builtin_amdgcn_s_setprio(0);
        // publish kh1(s): A_k1(s)[P3(s-1)], B_k1(s)[P4(s-1)] must be landed;
        // only A_k0(s+1) (2 gloads, this phase) may stay in flight.
        if (s == NT - 1) { VMCNT(0); } else { VMCNT(2); }
        BAR();

        // ---- P2: prefetch a03_k1 + b_k1; stage B_k0(s+1); MFMA m4-7 x kh0 ----
#pragma unroll
        for (int m = 0; m < 4; ++m) a0[m] = lda(b, 1, m);
#pragma unroll
        for (int n = 0; n < 4; ++n) b1[n] = ldb(b, 1, n);
        if (s + 1 < NT) stage(nb, 1, 0, Bbase, s + 1);
        BAR();
        __builtin_amdgcn_s_setprio(1);
#pragma unroll
        for (int m = 0; m < 4; ++m)
#pragma unroll
            for (int n = 0; n < 4; ++n)
                acc[4 + m][n] = MFMA16(a1[m], b0[n], acc[4 + m][n]);
        __builtin_amdgcn_s_setprio(0);

        // ---- P3: prefetch a47_k1; stage A_k1(s+1); MFMA m0-3 x kh1 ----
#pragma unroll
        for (int m = 0; m < 4; ++m) a1[m] = lda(b, 1, 4 + m);
        if (s + 1 < NT) stage(nb, 0, 1, Abase, s + 1);
        BAR();
        __builtin_amdgcn_s_setprio(1);
#pragma unroll
        for (int m = 0; m < 4; ++m)
#pragma unroll
            for (int n = 0; n < 4; ++n)
                acc[m][n] = MFMA16(a0[m], b1[n], acc[m][n]);
        __builtin_amdgcn_s_setprio(0);
        // publish kh0(s+1): A_k0(s+1)[P1], B_k0(s+1)[P2] landed; allow
        // A_k1(s+1)[P3] (2 gloads) in flight.
        if (s + 1 < NT) { VMCNT(2); BAR(); }

        // ---- P4: prefetch next-tile a03_k0 + b_k0; stage B_k1(s+1); MFMA m4-7 x kh1 ----
        if (s + 1 < NT) {
#pragma unroll
            for (int m = 0; m < 4; ++m) a0[m] = lda(nb, 0, m);
#pragma unroll
            for (int n = 0; n < 4; ++n) b0[n] = ldb(nb, 0, n);
            stage(nb, 1, 1, Bbase, s + 1);
        }
        BAR();
        __builtin_amdgcn_s_setprio(1);
#pragma unroll
        for (int m = 0; m < 4; ++m)
#pragma unroll
            for (int n = 0; n < 4; ++n)
                acc[4 + m][n] = MFMA16(a1[m], b1[n], acc[4 + m][n]);
        __builtin_amdgcn_s_setprio(0);
    }

    // ---------------- fused epilogue: scale + bias + quant + dequant ----
    const float wscale = wsp[0];
    const float oscale = osp[0];
    const int row0 = bm * BM + wm * 128;
    const int col0 = bn * BN + wn * 64;
#pragma unroll
    for (int n = 0; n < 4; ++n) {
        const int col = col0 + n * 16 + lr;
        const float bc = bias[col];
#pragma unroll
        for (int m = 0; m < 8; ++m) {
#pragma unroll
            for (int j = 0; j < 4; ++j) {
                const int row = row0 + m * 16 + kq * 4 + j;
                float y = acc[m][n][j] * wscale + bc;
                float q = rintf(y / oscale);          // round-half-even, matches jnp.round
                q = fminf(fmaxf(q, -128.0f), 127.0f);
                C[(size_t)row * O_FEAT + col] = q * oscale;
            }
        }
    }
}

extern "C" void kernel_launch(void* const* d_in, const int* in_sizes, int n_in,
                              void* d_out, int out_size, void* d_ws, size_t ws_size,
                              hipStream_t stream) {
    const float* x        = (const float*)d_in[0];  // [8192,4096] fp32
    const float* wq       = (const float*)d_in[1];  // [4096,4096] fp32 (int8 values)
    const float* bias     = (const float*)d_in[2];  // [4096]
    const float* w_scale  = (const float*)d_in[3];  // scalar
    const float* out_scale= (const float*)d_in[4];  // scalar
    const int*   mask     = (const int*)d_in[5];    // [4096,1024] int32
    float* out = (float*)d_out;

    _Float16* xf = (_Float16*)d_ws;                                        // 64 MiB
    _Float16* wf = (_Float16*)((char*)d_ws + (size_t)M_TOK * K_FEAT * 2);  // +32 MiB

    cvt_x_kernel<<<(M_TOK * (size_t)K_FEAT) / 8 / 256, 256, 0, stream>>>(x, xf);
    cvt_w_kernel<<<(O_FEAT * (size_t)K_FEAT) / 8 / 256, 256, 0, stream>>>(wq, mask, wf);

    // (8192/256) x (4096/256) = 32*16 = 512 blocks, 512 threads
    gemm_kernel<<<dim3((M_TOK / BM) * (O_FEAT / BN)), 512, 0, stream>>>(
        xf, wf, bias, w_scale, out_scale, out);
}